// Round 4
// baseline (304.384 us; speedup 1.0000x reference)
//
#include <hip/hip_runtime.h>

// ---------- types ----------
typedef __attribute__((ext_vector_type(8))) short bf16x8;   // 8 bf16 in 4 VGPRs
typedef __attribute__((ext_vector_type(4))) short bf16x4;   // 4 bf16 in 2 VGPRs
typedef __attribute__((ext_vector_type(4))) float f32x4;    // MFMA C/D

#define MFMA32(a,b,c) __builtin_amdgcn_mfma_f32_16x16x32_bf16((a),(b),(c),0,0,0)
#define MFMA16(a,b,c) __builtin_amdgcn_mfma_f32_16x16x16bf16_1k((a),(b),(c),0,0,0)
#define LOG2E 1.44269504f

// raw barrier: memory clobber orders LDS/global ops; register-only MFMA may
// float across (rule #18) — wanted here.
#define BAR() asm volatile("s_barrier" ::: "memory")
// two-level so macro args expand before stringization
#define VMW_(n) asm volatile("s_waitcnt vmcnt(" #n ")" ::: "memory")
#define VMW(n) VMW_(n)

__device__ __forceinline__ unsigned short f2bf(float f) {
  unsigned int u = __float_as_uint(f);
  u += 0x7fffu + ((u >> 16) & 1u);      // round-to-nearest-even
  return (unsigned short)(u >> 16);
}

// async global->LDS, 16B per lane; LDS dest = wave-uniform base + lane*16
__device__ __forceinline__ void cp16(const void* g, void* l) {
  __builtin_amdgcn_global_load_lds((const __attribute__((address_space(1))) void*)g,
                                   (__attribute__((address_space(3))) void*)l, 16, 0, 0);
}

// ---------- fp32 -> bf16 (query, memory) + bias pre-transform, one launch ----
__global__ void conv_both(const float* __restrict__ q, const float* __restrict__ m,
                          const float* __restrict__ bias,
                          unsigned short* __restrict__ qo, unsigned short* __restrict__ mo,
                          float* __restrict__ bz) {
  int i = blockIdx.x * 256 + threadIdx.x;   // grid covers 4718592 + 4096 float4s
  if (i < 524288) {
    float4 v = ((const float4*)q)[i];
    ushort4 o; o.x = f2bf(v.x); o.y = f2bf(v.y); o.z = f2bf(v.z); o.w = f2bf(v.w);
    ((ushort4*)qo)[i] = o;
  } else if (i < 4718592) {
    int j = i - 524288;
    float4 v = ((const float4*)m)[j];
    ushort4 o; o.x = f2bf(v.x); o.y = f2bf(v.y); o.z = f2bf(v.z); o.w = f2bf(v.w);
    ((ushort4*)mo)[j] = o;
  } else {
    int j = i - 4718592;                   // < 4096: bias -> bias*log2e - 16
    float4 v = ((const float4*)bias)[j];
    float4 o;
    o.x = __builtin_fmaf(v.x, LOG2E, -16.f);
    o.y = __builtin_fmaf(v.y, LOG2E, -16.f);
    o.z = __builtin_fmaf(v.z, LOG2E, -16.f);
    o.w = __builtin_fmaf(v.w, LOG2E, -16.f);
    ((float4*)bz)[j] = o;
  }
}

// ---------- 1024x1024 transpose+convert for all 4 weights in one launch ----------
__global__ void transpose4(const float* __restrict__ Wq, const float* __restrict__ Wk,
                           const float* __restrict__ Wv, const float* __restrict__ Wo,
                           unsigned short* __restrict__ dst) {
  __shared__ float t[32][33];
  int z = blockIdx.z;
  const float* W = (z == 0) ? Wq : (z == 1) ? Wk : (z == 2) ? Wv : Wo;
  unsigned short* WT = dst + (size_t)z * 1048576;
  int bx = blockIdx.x * 32, by = blockIdx.y * 32;
  int x = threadIdx.x, y0 = threadIdx.y;
#pragma unroll
  for (int r = 0; r < 4; ++r)
    t[y0 + r * 8][x] = W[(size_t)(by + y0 + r * 8) * 1024 + bx + x];
  __syncthreads();
#pragma unroll
  for (int r = 0; r < 4; ++r)
    WT[(size_t)(bx + y0 + r * 8) * 1024 + by + x] = f2bf(t[x][y0 + r * 8]);
}

// ---------- fused K/V projection — r9: fragment READ-AHEAD pipeline ----------
// r8 measured full LDS<->MFMA serialization (per tile: 4788 cyc serial model vs
// 5640 measured). Fix: issue phase p+1's fragment ds_reads at the TOP of
// section p, before section p's MFMA (whose operands landed in section p-1).
// Compiler's count-based lgkm wait then lets the 8 new reads fly during the
// MFMA cluster -> LDS pipe (768/384 cyc) overlaps matrix pipe (621 cyc).
// Register rotation (no copies): aE/aO = A khalf0/1 of current tile;
// bP/bQ rotate so each read's target was last consumed one phase earlier:
//   ph0: rd aO<-a1(t), bQ<-bk1(t); STG K(t+1); MFMA acck += aE*bP  (a0*bk0)
//   ph1: VMW(6); rd bP<-bv0(t);    STG V(t+1); MFMA acck += aO*bQ  (a1*bk1)
//   ph2: rd bQ<-bv1(t);            STG A(t+2)lo; MFMA accv += aE*bP (a0*bv0)
//   ph3: VMW(4); rd aE<-a0(t+1), bP<-bk0(t+1); STG A(t+2)hi; MFMA accv+=aO*bQ
// One barrier per phase (at top, after VMW). Staging-region safety: every STG
// region's readers are >=2 sections old; the lgkm wait inside the intervening
// MFMA cluster + barrier transitively forces all waves' reads complete first.
// vmcnt FIFO: entry ph1: [V(t)2,A(t+1)4,K(t+1)2]=8 -> VMW(6) retires V(t);
// entry ph3: 10 -> VMW(4) retires A(t+1)+K(t+1). Tails: t=14 VMW(2)@ph3,
// t=15 VMW(0)@ph1 (drain). T2 swizzle + T5 setprio unchanged.
__global__ __launch_bounds__(512, 2) void gemm_kv(
    const unsigned short* __restrict__ A,   // mbf [16384][1024]
    const unsigned short* __restrict__ Bk,  // WkT [1024][1024]
    const unsigned short* __restrict__ Bv,  // WvT [1024][1024]
    unsigned short* __restrict__ Kp,        // [16384][1024]
    unsigned short* __restrict__ Vt)        // [1024][16384]
{
  // buffer b at b*32768 ushorts: A[256][64]@0, Bk[128][64]@16384, Bv@24576
  __shared__ __attribute__((aligned(16))) unsigned short lds[65536]; // 128 KB
  const int tid = threadIdx.x;
  const int w = tid >> 6, lane = tid & 63;
  const int lh = lane & 15, q4 = lane >> 4;
  const int id = blockIdx.x;
  const int xcd = id & 7, j = id >> 3;
  const int tm = (xcd * 8 + (j >> 3)) * 256;  // 8 m-strips per XCD, n inner
  const int tn = (j & 7) * 128;
  const int wm = (w >> 1) * 64, wn = (w & 1) * 64;

  // staging lane geometry (source-side T2 swizzle, 64B row segments stay whole)
  const int r8 = lane >> 3;                       // row within 8-row chunk
  const int scol = ((lane & 7) ^ r8) * 8;         // swizzled source k-slot
  const int srow = w * 8 + r8;                    // row within 64-row chunk
  // fragment-read swizzled slot offsets (row&7 == lh&7 for all frag rows)
  const int fs0 = ((0 + q4) ^ (lh & 7)) * 8;
  const int fs1 = ((4 + q4) ^ (lh & 7)) * 8;

  const unsigned short* Ag = A  + (size_t)tm * 1024 + scol;
  const unsigned short* Kg = Bk + (size_t)tn * 1024 + scol;
  const unsigned short* Vg = Bv + (size_t)tn * 1024 + scol;

#define STG_A(BUF,KT,I) cp16(Ag + (size_t)((I)*64 + srow) * 1024 + (KT)*64, \
                             lds + (BUF)*32768 + (I)*4096 + w*512)
#define STG_K(BUF,KT,I) cp16(Kg + (size_t)((I)*64 + srow) * 1024 + (KT)*64, \
                             lds + (BUF)*32768 + 16384 + (I)*4096 + w*512)
#define STG_V(BUF,KT,I) cp16(Vg + (size_t)((I)*64 + srow) * 1024 + (KT)*64, \
                             lds + (BUF)*32768 + 24576 + (I)*4096 + w*512)

  f32x4 acck[4][4] = {}, accv[4][4] = {};
  bf16x8 aE[4], aO[4], bP[4], bQ[4];   // persistent rotating fragment regs

  // ---- prologue: A(0)x4, K(0)x2, V(0)x2, A(1)x4; retire A(0)+K(0); preload
  STG_A(0, 0, 0); STG_A(0, 0, 1); STG_A(0, 0, 2); STG_A(0, 0, 3);
  STG_K(0, 0, 0); STG_K(0, 0, 1);
  STG_V(0, 0, 0); STG_V(0, 0, 1);
  STG_A(1, 1, 0); STG_A(1, 1, 1); STG_A(1, 1, 2); STG_A(1, 1, 3);
  VMW(6);
  BAR();
#pragma unroll
  for (int m = 0; m < 4; ++m)
    aE[m] = *(const bf16x8*)(lds + (wm + m * 16 + lh) * 64 + fs0);
#pragma unroll
  for (int n = 0; n < 4; ++n)
    bP[n] = *(const bf16x8*)(lds + 16384 + (wn + n * 16 + lh) * 64 + fs0);

#define KV_TILE(CURB, TP1, TP2, DO_SB, DO_SA, VM1N, VM3N, DO_V3, DO_RDN)      \
  {                                                                           \
    const unsigned short* bse = lds + (CURB) * 32768;                         \
    const unsigned short* bnx = lds + ((CURB) ^ 1) * 32768;                   \
    const int nx = (CURB) ^ 1;                                                \
    /* ph0: rd a1/bk1(t); STG K(t+1); MFMA K: aE*bP */                        \
    BAR();                                                                    \
    _Pragma("unroll") for (int m = 0; m < 4; ++m)                             \
      aO[m] = *(const bf16x8*)(bse + (wm + m * 16 + lh) * 64 + fs1);          \
    _Pragma("unroll") for (int n = 0; n < 4; ++n)                             \
      bQ[n] = *(const bf16x8*)(bse + 16384 + (wn + n * 16 + lh) * 64 + fs1);  \
    if (DO_SB) { STG_K(nx, TP1, 0); STG_K(nx, TP1, 1); }                      \
    __builtin_amdgcn_s_setprio(1);                                            \
    _Pragma("unroll") for (int m = 0; m < 4; ++m)                             \
      _Pragma("unroll") for (int n = 0; n < 4; ++n)                           \
        acck[m][n] = MFMA32(aE[m], bP[n], acck[m][n]);                        \
    __builtin_amdgcn_s_setprio(0);                                            \
    /* ph1: VMW; rd bv0(t)->bP; STG V(t+1); MFMA K: aO*bQ */                  \
    VMW(VM1N);                                                                \
    BAR();                                                                    \
    _Pragma("unroll") for (int n = 0; n < 4; ++n)                             \
      bP[n] = *(const bf16x8*)(bse + 24576 + (wn + n * 16 + lh) * 64 + fs0);  \
    if (DO_SB) { STG_V(nx, TP1, 0); STG_V(nx, TP1, 1); }                      \
    __builtin_amdgcn_s_setprio(1);                                            \
    _Pragma("unroll") for (int m = 0; m < 4; ++m)                             \
      _Pragma("unroll") for (int n = 0; n < 4; ++n)                           \
        acck[m][n] = MFMA32(aO[m], bQ[n], acck[m][n]);                        \
    __builtin_amdgcn_s_setprio(0);                                            \
    /* ph2: rd bv1(t)->bQ; STG A(t+2)lo; MFMA V: aE*bP */                     \
    BAR();                                                                    \
    _Pragma("unroll") for (int n = 0; n < 4; ++n)                             \
      bQ[n] = *(const bf16x8*)(bse + 24576 + (wn + n * 16 + lh) * 64 + fs1);  \
    if (DO_SA) { STG_A(CURB, TP2, 0); STG_A(CURB, TP2, 1); }                  \
    __builtin_amdgcn_s_setprio(1);                                            \
    _Pragma("unroll") for (int m = 0; m < 4; ++m)                             \
      _Pragma("unroll") for (int n = 0; n < 4; ++n)                           \
        accv[m][n] = MFMA32(aE[m], bP[n], accv[m][n]);                        \
    __builtin_amdgcn_s_setprio(0);                                            \
    /* ph3: VMW; rd a0/bk0(t+1); STG A(t+2)hi; MFMA V: aO*bQ */               \
    if (DO_V3) { VMW(VM3N); }                                                 \
    BAR();                                                                    \
    if (DO_RDN) {                                                             \
      _Pragma("unroll") for (int m = 0; m < 4; ++m)                           \
        aE[m] = *(const bf16x8*)(bnx + (wm + m * 16 + lh) * 64 + fs0);        \
      _Pragma("unroll") for (int n = 0; n < 4; ++n)                           \
        bP[n] = *(const bf16x8*)(bnx + 16384 + (wn + n * 16 + lh) * 64 + fs0);\
    }                                                                         \
    if (DO_SA) { STG_A(CURB, TP2, 2); STG_A(CURB, TP2, 3); }                  \
    __builtin_amdgcn_s_setprio(1);                                            \
    _Pragma("unroll") for (int m = 0; m < 4; ++m)                             \
      _Pragma("unroll") for (int n = 0; n < 4; ++n)                           \
        accv[m][n] = MFMA32(aO[m], bQ[n], accv[m][n]);                        \
    __builtin_amdgcn_s_setprio(0);                                            \
  }

  for (int t = 0; t < 14; ++t) {
    KV_TILE(t & 1, t + 1, t + 2, 1, 1, 6, 4, 1, 1);
  }
  KV_TILE(0, 15, 16, 1, 0, 6, 2, 1, 1);   // t=14: stage K/V(15) only
  KV_TILE(1, 16, 17, 0, 0, 0, 0, 0, 0);   // t=15: drain (VMW(0) at ph1)

#undef KV_TILE
#undef STG_A
#undef STG_K
#undef STG_V

  // Kp epilogue: row-major 2B stores coalesce within lh groups (r4-verified)
#pragma unroll
  for (int m = 0; m < 4; ++m)
#pragma unroll
    for (int n = 0; n < 4; ++n) {
      int row = tm + wm + m * 16 + q4 * 4;
      int col = tn + wn + n * 16 + lh;
#pragma unroll
      for (int e = 0; e < 4; ++e)
        Kp[(size_t)(row + e) * 1024 + col] = f2bf(acck[m][n][e]);
    }

  // Vt epilogue via LDS: write C-layout (xor-swizzled 256-row tile), read back
  // coalesced (2-way write aliasing = free; readback 512B-contiguous per col).
  __syncthreads();
#pragma unroll
  for (int m = 0; m < 4; ++m)
#pragma unroll
    for (int n = 0; n < 4; ++n) {
      int row = wm + m * 16 + q4 * 4;       // block-local token (+e consecutive)
      int col = wn + n * 16 + lh;           // block-local d
      ushort4 v4;
      v4.x = f2bf(accv[m][n][0]); v4.y = f2bf(accv[m][n][1]);
      v4.z = f2bf(accv[m][n][2]); v4.w = f2bf(accv[m][n][3]);
      *(ushort4*)(lds + col * 256 + (row ^ ((col & 31) << 3))) = v4;
    }
  __syncthreads();
#pragma unroll
  for (int p = 0; p < 8; ++p) {
    int col = p * 16 + (tid >> 5);                  // 0..127
    int jb = tid & 31;                              // 8-ushort block in 256 rows
    const unsigned short* src = lds + col * 256 + ((jb ^ (col & 31)) << 3);
    *(int4*)(Vt + (size_t)(tn + col) * 16384 + tm + jb * 8) = *(const int4*)src;
  }
}

// ---------- bf16 GEMM 128x64 tile (q-proj, out-proj) ----------
// r6 T2 swizzle retained.
__global__ __launch_bounds__(256) void gemm_bt64(
    const unsigned short* __restrict__ A, const unsigned short* __restrict__ B,
    float* __restrict__ Cf, unsigned short* __restrict__ Cb,
    int M, int N, int K, float scale)
{
  __shared__ __attribute__((aligned(16))) unsigned short lds[6144]; // A[128][32]@0, B[64][32]@4096
  int w = threadIdx.x >> 6, lane = threadIdx.x & 63;
  int lh = lane & 15, q4 = lane >> 4;
  int tm = blockIdx.y * 128, tn = blockIdx.x * 64;
  int wm = (w & 1) * 64, wn = (w >> 1) * 32;

  int srow = lane >> 2;
  int scol = ((lane & 3) ^ ((lane >> 3) & 3)) << 3;
  int q4s = (q4 ^ ((lh >> 1) & 3)) << 3;

  f32x4 acc[4][2] = {};

  for (int k0 = 0; k0 < K; k0 += 32) {
#pragma unroll
    for (int i = 0; i < 2; ++i) {
      int c = w * 2 + i;
      int row = c * 16 + srow;
      cp16(A + (size_t)(tm + row) * K + k0 + scol, lds + c * 512);
    }
    {
      int row = w * 16 + srow;
      cp16(B + (size_t)(tn + row) * K + k0 + scol, lds + 4096 + w * 512);
    }
    __syncthreads();
    bf16x8 afr[4], bfr[2];
#pragma unroll
    for (int r = 0; r < 4; ++r)
      afr[r] = *(const bf16x8*)(lds + (wm + r * 16 + lh) * 32 + q4s);
#pragma unroll
    for (int c = 0; c < 2; ++c)
      bfr[c] = *(const bf16x8*)(lds + 4096 + (wn + c * 16 + lh) * 32 + q4s);
#pragma unroll
    for (int r = 0; r < 4; ++r)
#pragma unroll
      for (int c = 0; c < 2; ++c)
        acc[r][c] = MFMA32(afr[r], bfr[c], acc[r][c]);
    __syncthreads();
  }

#pragma unroll
  for (int r = 0; r < 4; ++r)
#pragma unroll
    for (int c = 0; c < 2; ++c)
#pragma unroll
      for (int e = 0; e < 4; ++e) {
        int row = tm + wm + r * 16 + q4 * 4 + e;
        int col = tn + wn + c * 16 + lh;
        if (Cb) Cb[(size_t)row * N + col] = f2bf(acc[r][c][e] * scale);
        else    Cf[(size_t)row * N + col] = acc[r][c][e] * scale;
      }
}

// ---------- attention v4 (round-5 proven): LDS-staged K/V, register P -------
__global__ __launch_bounds__(256) void attn_kernel(
    const unsigned short* __restrict__ Q, const unsigned short* __restrict__ Kp,
    const unsigned short* __restrict__ VT, const float* __restrict__ bz,
    float* __restrict__ po, float* __restrict__ lp)
{
  __shared__ __attribute__((aligned(16))) unsigned short Klds[4096]; // [64 tok][8 blk of 8]
  __shared__ __attribute__((aligned(16))) unsigned short Vlds[4096]; // [64 d][8 blk of 8]
  int w = threadIdx.x >> 6, lane = threadIdx.x & 63;
  int lh = lane & 15, q4 = lane >> 4;

  // XCD swizzle: same-bh blocks land on same XCD (bh & 7 == xcd)
  int id = blockIdx.x;
  int xcd = id & 7, j = id >> 3;
  int ql = j & 7;                   // 8 blocks per bh
  int half = ql & 1, qt = ql >> 1;  // token half, q-tile
  int bh = (j >> 3) * 8 + xcd;
  int b = bh >> 4, h = bh & 15;
  int q0 = qt * 128;
  int t00 = half * 2048;

  const unsigned short* Qb = Q + (size_t)(b * 512 + q0 + w * 32) * 1024 + h * 64;
  const unsigned short* Kb = Kp + (size_t)(b * 4096) * 1024 + h * 64;
  const unsigned short* Vb = VT + (size_t)(h * 64) * 16384 + b * 4096;
  const float* bzg = bz + (size_t)b * 4096;

  // Q B-operand fragments: 2 strips of 16 q-rows
  bf16x8 bq[2][2];
#pragma unroll
  for (int s = 0; s < 2; ++s)
#pragma unroll
    for (int th = 0; th < 2; ++th)
      bq[s][th] = *(const bf16x8*)(Qb + (size_t)(s * 16 + lh) * 1024 + th * 32 + q4 * 8);

  f32x4 oa[2][4] = {};              // O^T accumulators [strip][d-tile]
  float ls[2] = {0.f, 0.f};

  int rl = lane >> 3, blk = lane & 7;
  int sw = ((blk ^ rl) * 8);        // xor-swizzled 8-ushort block offset in source row

  for (int ti = 0; ti < 32; ++ti) {
    int t = t00 + ti * 64;
    // ---- stage K[64 tok][64 d] and V^T[64 d][64 tok], xor-swizzled blocks ----
#pragma unroll
    for (int r = 0; r < 2; ++r) {
      int seg = r * 4 + w;
      int row = seg * 8 + rl;
      cp16(Kb + (size_t)(t + row) * 1024 + sw, Klds + seg * 512);
      cp16(Vb + (size_t)row * 16384 + t + sw, Vlds + seg * 512);
    }
    __syncthreads();

    // bias (pre-transformed) for this tile's tokens
    float4 bz4[4];
#pragma unroll
    for (int c = 0; c < 4; ++c)
      bz4[c] = *(const float4*)(bzg + t + c * 16 + q4 * 4);

    // K fragments: A[m=tok][k=d], lane m=lh, k=th*32+q4*8..+8
    bf16x8 kf[4][2];
#pragma unroll
    for (int c = 0; c < 4; ++c)
#pragma unroll
      for (int th = 0; th < 2; ++th)
        kf[c][th] = *(const bf16x8*)(Klds + (c * 16 + lh) * 64 + (((th << 2) + q4) ^ (lh & 7)) * 8);
    // V fragments: A[m=d][k=tok], lane m=lh (+c2*16), k=c*16+q4*4..+4
    bf16x4 vf[4][4];
#pragma unroll
    for (int c = 0; c < 4; ++c)
#pragma unroll
      for (int c2 = 0; c2 < 4; ++c2)
        vf[c][c2] = *(const bf16x4*)(Vlds + (c2 * 16 + lh) * 64 +
                                     (((c << 1) + (q4 >> 1)) ^ (lh & 7)) * 8 + (q4 & 1) * 4);

#pragma unroll
    for (int s = 0; s < 2; ++s) {
#pragma unroll
      for (int c = 0; c < 4; ++c) {
        f32x4 z = {};
        z = MFMA32(kf[c][0], bq[s][0], z);
        z = MFMA32(kf[c][1], bq[s][1], z);
        float bzf[4] = {bz4[c].x, bz4[c].y, bz4[c].z, bz4[c].w};
        bf16x4 pb;
        float ps = 0.f;
#pragma unroll
        for (int e = 0; e < 4; ++e) {
          float p = __builtin_amdgcn_exp2f(z[e] + bzf[e]);
          ps += p;
          pb[e] = (short)f2bf(p);
        }
        ls[s] += ps;
#pragma unroll
        for (int c2 = 0; c2 < 4; ++c2)
          oa[s][c2] = MFMA16(vf[c][c2], pb, oa[s][c2]);
      }
    }
    __syncthreads();
  }

  // l: lane holds partial for q=lh; reduce across the 4 q4 groups
#pragma unroll
  for (int s = 0; s < 2; ++s) {
    ls[s] += __shfl_xor(ls[s], 16);
    ls[s] += __shfl_xor(ls[s], 32);
  }

  // partial stores: po[half*256 + bh*4+qt][d=64][q=128]
  int sl = bh * 4 + qt;
  float* pslice = po + (size_t)(half * 256 + sl) * 8192;
#pragma unroll
  for (int s = 0; s < 2; ++s) {
    if (q4 == 0) lp[half * 32768 + sl * 128 + w * 32 + s * 16 + lh] = ls[s];
#pragma unroll
    for (int c2 = 0; c2 < 4; ++c2)
#pragma unroll
      for (int e = 0; e < 4; ++e)
        pslice[(c2 * 16 + q4 * 4 + e) * 128 + w * 32 + s * 16 + lh] = oa[s][c2][e];
  }
}

// ---------- merge token-half partials, normalize, pack to bf16 ao ----------
__global__ void norm_kernel(const float* __restrict__ po, const float* __restrict__ lp,
                            unsigned short* __restrict__ ao) {
  int g = blockIdx.x * 256 + threadIdx.x;   // 262144 threads
  int d8 = (g & 7) * 8;
  int rowid = g >> 3;                        // 0..32767 = bh*512 + qt*128 + qcol
  int bh = rowid >> 9, rq = rowid & 511, qt = rq >> 7, qcol = rq & 127;
  int sl = bh * 4 + qt;
  const float* p0 = po + (size_t)sl * 8192;
  const float* p1 = po + (size_t)(256 + sl) * 8192;
  float l = lp[sl * 128 + qcol] + lp[32768 + sl * 128 + qcol];
  float inv = 1.f / l;
  unsigned short o8[8];
#pragma unroll
  for (int k = 0; k < 8; ++k)
    o8[k] = f2bf((p0[(d8 + k) * 128 + qcol] + p1[(d8 + k) * 128 + qcol]) * inv);
  int b = bh >> 4, h = bh & 15;
  unsigned short* dst = ao + (size_t)(b * 512 + qt * 128 + qcol) * 1024 + h * 64 + d8;
  *(ushort4*)dst = *(ushort4*)o8;
  *(ushort4*)(dst + 4) = *(ushort4*)(o8 + 4);
}

// ---------- launch ----------
extern "C" void kernel_launch(void* const* d_in, const int* in_sizes, int n_in,
                              void* d_out, int out_size, void* d_ws, size_t ws_size,
                              hipStream_t stream) {
  const float* query  = (const float*)d_in[0];
  const float* memory = (const float*)d_in[1];
  const float* bias   = (const float*)d_in[2];
  const float* Wq     = (const float*)d_in[3];
  const float* Wk     = (const float*)d_in[4];
  const float* Wv     = (const float*)d_in[5];
  const float* Wo     = (const float*)d_in[6];
  float* out = (float*)d_out;

  unsigned short* ws  = (unsigned short*)d_ws;
  unsigned short* qbf = ws;                       // 2048*1024
  unsigned short* mbf = qbf + 2097152;            // 16384*1024
  unsigned short* WqT = mbf + 16777216;           // 4 x 1024*1024 contiguous
  unsigned short* WkT = WqT + 1048576;
  unsigned short* WvT = WkT + 1048576;
  unsigned short* WoT = WvT + 1048576;
  unsigned short* qp  = WoT + 1048576;            // 2048*1024 (scaled q proj)
  unsigned short* kp  = qp + 2097152;             // 16384*1024
  unsigned short* vT  = kp + 16777216;            // 1024*16384
  unsigned short* ao  = vT + 16777216;            // 2048*1024
  float* bzw = (float*)(ao + 2097152);            // 16384 floats (bias*log2e-16)
  // po/lp alias qbf+mbf (dead after the projection GEMMs)
  float* po = (float*)ws;                         // 512 slices x 8192 floats = 16 MB
  float* lp = po + 4194304;                       // 65536 floats

  conv_both<<<18448, 256, 0, stream>>>(query, memory, bias, qbf, mbf, bzw);
  transpose4<<<dim3(32, 32, 4), dim3(32, 8), 0, stream>>>(Wq, Wk, Wv, Wo, WqT);

  // q = (query@Wq) * (1/8)*log2e   [2048 x 1024]
  gemm_bt64<<<dim3(16, 16), 256, 0, stream>>>(qbf, WqT, nullptr, qp, 2048, 1024, 1024, 0.125f * LOG2E);
  // fused: kp = memory@Wk, vT = (memory@Wv)^T  — read-ahead pipeline, 512 thr
  gemm_kv<<<512, 512, 0, stream>>>(mbf, WkT, WvT, kp, vT);

  attn_kernel<<<512, 256, 0, stream>>>(qp, kp, vT, bzw, po, lp);
  norm_kernel<<<1024, 256, 0, stream>>>(po, lp, ao);

  // out = ao @ Wo (fp32 out)
  gemm_bt64<<<dim3(16, 16), 256, 0, stream>>>(ao, WoT, out, nullptr, 2048, 1024, 1024, 1.f);
}

// Round 6
// 289.691 us; speedup vs baseline: 1.0507x; 1.0507x over previous
//
#include <hip/hip_runtime.h>

// ---------- types ----------
typedef __attribute__((ext_vector_type(8))) short bf16x8;   // 8 bf16 in 4 VGPRs
typedef __attribute__((ext_vector_type(4))) short bf16x4;   // 4 bf16 in 2 VGPRs
typedef __attribute__((ext_vector_type(4))) float f32x4;    // MFMA C/D

#define MFMA32(a,b,c) __builtin_amdgcn_mfma_f32_16x16x32_bf16((a),(b),(c),0,0,0)
#define MFMA16(a,b,c) __builtin_amdgcn_mfma_f32_16x16x16bf16_1k((a),(b),(c),0,0,0)
#define LOG2E 1.44269504f

__device__ __forceinline__ unsigned short f2bf(float f) {
  unsigned int u = __float_as_uint(f);
  u += 0x7fffu + ((u >> 16) & 1u);      // round-to-nearest-even
  return (unsigned short)(u >> 16);
}

// async global->LDS, 16B per lane; LDS dest = wave-uniform base + lane*16
__device__ __forceinline__ void cp16(const void* g, void* l) {
  __builtin_amdgcn_global_load_lds((const __attribute__((address_space(1))) void*)g,
                                   (__attribute__((address_space(3))) void*)l, 16, 0, 0);
}

// ---------- fp32 -> bf16 (query, memory) + bias pre-transform, one launch ----
__global__ void conv_both(const float* __restrict__ q, const float* __restrict__ m,
                          const float* __restrict__ bias,
                          unsigned short* __restrict__ qo, unsigned short* __restrict__ mo,
                          float* __restrict__ bz) {
  int i = blockIdx.x * 256 + threadIdx.x;   // grid covers 4718592 + 4096 float4s
  if (i < 524288) {
    float4 v = ((const float4*)q)[i];
    ushort4 o; o.x = f2bf(v.x); o.y = f2bf(v.y); o.z = f2bf(v.z); o.w = f2bf(v.w);
    ((ushort4*)qo)[i] = o;
  } else if (i < 4718592) {
    int j = i - 524288;
    float4 v = ((const float4*)m)[j];
    ushort4 o; o.x = f2bf(v.x); o.y = f2bf(v.y); o.z = f2bf(v.z); o.w = f2bf(v.w);
    ((ushort4*)mo)[j] = o;
  } else {
    int j = i - 4718592;                   // < 4096: bias -> bias*log2e - 16
    float4 v = ((const float4*)bias)[j];
    float4 o;
    o.x = __builtin_fmaf(v.x, LOG2E, -16.f);
    o.y = __builtin_fmaf(v.y, LOG2E, -16.f);
    o.z = __builtin_fmaf(v.z, LOG2E, -16.f);
    o.w = __builtin_fmaf(v.w, LOG2E, -16.f);
    ((float4*)bz)[j] = o;
  }
}

// ---------- 1024x1024 transpose+convert for all 4 weights in one launch ----------
__global__ void transpose4(const float* __restrict__ Wq, const float* __restrict__ Wk,
                           const float* __restrict__ Wv, const float* __restrict__ Wo,
                           unsigned short* __restrict__ dst) {
  __shared__ float t[32][33];
  int z = blockIdx.z;
  const float* W = (z == 0) ? Wq : (z == 1) ? Wk : (z == 2) ? Wv : Wo;
  unsigned short* WT = dst + (size_t)z * 1048576;
  int bx = blockIdx.x * 32, by = blockIdx.y * 32;
  int x = threadIdx.x, y0 = threadIdx.y;
#pragma unroll
  for (int r = 0; r < 4; ++r)
    t[y0 + r * 8][x] = W[(size_t)(by + y0 + r * 8) * 1024 + bx + x];
  __syncthreads();
#pragma unroll
  for (int r = 0; r < 4; ++r)
    WT[(size_t)(bx + y0 + r * 8) * 1024 + by + x] = f2bf(t[x][y0 + r * 8]);
}

// ---------- fused K/V projection — r11: single-SYNC double-buffer -----------
// r10 race fix: raw s_barrier let hipcc sink register-only MFMAs (and their
// lgkm waits) past it (rule #18) -> a wave could cross the barrier with tile-t
// ds_reads outstanding while another wave cp16-overwrites that buffer. Fix:
// __syncthreads() (vmcnt(0)+lgkmcnt(0)+s_barrier) at the tile TOP. The
// lgkmcnt(0) closes the race; the vmcnt(0) replaces the old end-of-tile
// VMW(0) one tile LATER -> stages stay in flight across the whole 64-MFMA
// compute span. Structure per tile:
//   __syncthreads(); [stage t+1 -> buf nx, 8 cp16/thr]; 24 frag ds_reads
//   from buf cur; 64 MFMA (one unbroken compiler-scheduled region).
// One sync per 64 MFMA vs m97's 2 per 16. Hazards: (a) tile-t reads drained
// by lgkmcnt(0) at sync(t+1) before any wave stages into that buffer after
// the barrier; (b) tile-t+1 stages drained by vmcnt(0) at sync(t+1) before
// any wave reads them. T2 swizzle + T5 setprio retained.
__global__ __launch_bounds__(512, 2) void gemm_kv(
    const unsigned short* __restrict__ A,   // mbf [16384][1024]
    const unsigned short* __restrict__ Bk,  // WkT [1024][1024]
    const unsigned short* __restrict__ Bv,  // WvT [1024][1024]
    unsigned short* __restrict__ Kp,        // [16384][1024]
    unsigned short* __restrict__ Vt)        // [1024][16384]
{
  // buffer b at b*32768 ushorts: A[256][64]@0, Bk[128][64]@16384, Bv@24576
  __shared__ __attribute__((aligned(16))) unsigned short lds[65536]; // 128 KB
  const int tid = threadIdx.x;
  const int w = tid >> 6, lane = tid & 63;
  const int lh = lane & 15, q4 = lane >> 4;
  const int id = blockIdx.x;
  const int xcd = id & 7, j = id >> 3;
  const int tm = (xcd * 8 + (j >> 3)) * 256;  // 8 m-strips per XCD, n inner
  const int tn = (j & 7) * 128;
  const int wm = (w >> 1) * 64, wn = (w & 1) * 64;

  // staging lane geometry (source-side T2 swizzle, 64B row segments stay whole)
  const int r8 = lane >> 3;                       // row within 8-row chunk
  const int scol = ((lane & 7) ^ r8) * 8;         // swizzled source k-slot
  const int srow = w * 8 + r8;                    // row within 64-row chunk
  // fragment-read swizzled slot offsets (row&7 == lh&7 for all frag rows)
  const int fs0 = ((0 + q4) ^ (lh & 7)) * 8;
  const int fs1 = ((4 + q4) ^ (lh & 7)) * 8;

  const unsigned short* Ag = A  + (size_t)tm * 1024 + scol;
  const unsigned short* Kg = Bk + (size_t)tn * 1024 + scol;
  const unsigned short* Vg = Bv + (size_t)tn * 1024 + scol;

#define STG_A(BUF,KT,I) cp16(Ag + (size_t)((I)*64 + srow) * 1024 + (KT)*64, \
                             lds + (BUF)*32768 + (I)*4096 + w*512)
#define STG_K(BUF,KT,I) cp16(Kg + (size_t)((I)*64 + srow) * 1024 + (KT)*64, \
                             lds + (BUF)*32768 + 16384 + (I)*4096 + w*512)
#define STG_V(BUF,KT,I) cp16(Vg + (size_t)((I)*64 + srow) * 1024 + (KT)*64, \
                             lds + (BUF)*32768 + 24576 + (I)*4096 + w*512)

  f32x4 acck[4][4] = {}, accv[4][4] = {};

  // ---- prologue: stage tile 0 into buf 0 (drained by first __syncthreads)
  STG_A(0, 0, 0); STG_A(0, 0, 1); STG_A(0, 0, 2); STG_A(0, 0, 3);
  STG_K(0, 0, 0); STG_K(0, 0, 1);
  STG_V(0, 0, 0); STG_V(0, 0, 1);

  for (int t = 0; t < 16; ++t) {
    const unsigned short* bse = lds + (t & 1) * 32768;
    const int nx = (t & 1) ^ 1;
    __syncthreads();                 // vmcnt(0)+lgkmcnt(0)+s_barrier
    if (t < 15) {
      STG_A(nx, t + 1, 0); STG_A(nx, t + 1, 1);
      STG_A(nx, t + 1, 2); STG_A(nx, t + 1, 3);
      STG_K(nx, t + 1, 0); STG_K(nx, t + 1, 1);
      STG_V(nx, t + 1, 0); STG_V(nx, t + 1, 1);
    }
    // kh = 0
    {
      bf16x8 a0[4], bk0[4], bv0[4];
#pragma unroll
      for (int m = 0; m < 4; ++m)
        a0[m] = *(const bf16x8*)(bse + (wm + m * 16 + lh) * 64 + fs0);
#pragma unroll
      for (int n = 0; n < 4; ++n) {
        bk0[n] = *(const bf16x8*)(bse + 16384 + (wn + n * 16 + lh) * 64 + fs0);
        bv0[n] = *(const bf16x8*)(bse + 24576 + (wn + n * 16 + lh) * 64 + fs0);
      }
      __builtin_amdgcn_s_setprio(1);
#pragma unroll
      for (int m = 0; m < 4; ++m)
#pragma unroll
        for (int n = 0; n < 4; ++n) {
          acck[m][n] = MFMA32(a0[m], bk0[n], acck[m][n]);
          accv[m][n] = MFMA32(a0[m], bv0[n], accv[m][n]);
        }
      __builtin_amdgcn_s_setprio(0);
    }
    // kh = 1
    {
      bf16x8 a1[4], bk1[4], bv1[4];
#pragma unroll
      for (int m = 0; m < 4; ++m)
        a1[m] = *(const bf16x8*)(bse + (wm + m * 16 + lh) * 64 + fs1);
#pragma unroll
      for (int n = 0; n < 4; ++n) {
        bk1[n] = *(const bf16x8*)(bse + 16384 + (wn + n * 16 + lh) * 64 + fs1);
        bv1[n] = *(const bf16x8*)(bse + 24576 + (wn + n * 16 + lh) * 64 + fs1);
      }
      __builtin_amdgcn_s_setprio(1);
#pragma unroll
      for (int m = 0; m < 4; ++m)
#pragma unroll
        for (int n = 0; n < 4; ++n) {
          acck[m][n] = MFMA32(a1[m], bk1[n], acck[m][n]);
          accv[m][n] = MFMA32(a1[m], bv1[n], accv[m][n]);
        }
      __builtin_amdgcn_s_setprio(0);
    }
  }

#undef STG_A
#undef STG_K
#undef STG_V

  // Kp epilogue: row-major 2B stores coalesce within lh groups (r4-verified)
#pragma unroll
  for (int m = 0; m < 4; ++m)
#pragma unroll
    for (int n = 0; n < 4; ++n) {
      int row = tm + wm + m * 16 + q4 * 4;
      int col = tn + wn + n * 16 + lh;
#pragma unroll
      for (int e = 0; e < 4; ++e)
        Kp[(size_t)(row + e) * 1024 + col] = f2bf(acck[m][n][e]);
    }

  // Vt epilogue via LDS: write C-layout (xor-swizzled 256-row tile), read back
  // coalesced (2-way write aliasing = free; readback 512B-contiguous per col).
  __syncthreads();
#pragma unroll
  for (int m = 0; m < 4; ++m)
#pragma unroll
    for (int n = 0; n < 4; ++n) {
      int row = wm + m * 16 + q4 * 4;       // block-local token (+e consecutive)
      int col = wn + n * 16 + lh;           // block-local d
      ushort4 v4;
      v4.x = f2bf(accv[m][n][0]); v4.y = f2bf(accv[m][n][1]);
      v4.z = f2bf(accv[m][n][2]); v4.w = f2bf(accv[m][n][3]);
      *(ushort4*)(lds + col * 256 + (row ^ ((col & 31) << 3))) = v4;
    }
  __syncthreads();
#pragma unroll
  for (int p = 0; p < 8; ++p) {
    int col = p * 16 + (tid >> 5);                  // 0..127
    int jb = tid & 31;                              // 8-ushort block in 256 rows
    const unsigned short* src = lds + col * 256 + ((jb ^ (col & 31)) << 3);
    *(int4*)(Vt + (size_t)(tn + col) * 16384 + tm + jb * 8) = *(const int4*)src;
  }
}

// ---------- bf16 GEMM 128x64 tile (q-proj, out-proj) ----------
// r11: single-sync double-buffer (same proof as gemm_kv); r6 T2 swizzle.
__global__ __launch_bounds__(256) void gemm_bt64(
    const unsigned short* __restrict__ A, const unsigned short* __restrict__ B,
    float* __restrict__ Cf, unsigned short* __restrict__ Cb,
    int M, int N, int K, float scale)
{
  // buffer b at b*6144 ushorts: A[128][32]@0, B[64][32]@4096
  __shared__ __attribute__((aligned(16))) unsigned short lds[12288]; // 24 KB
  int w = threadIdx.x >> 6, lane = threadIdx.x & 63;
  int lh = lane & 15, q4 = lane >> 4;
  int tm = blockIdx.y * 128, tn = blockIdx.x * 64;
  int wm = (w & 1) * 64, wn = (w >> 1) * 32;

  int srow = lane >> 2;
  int scol = ((lane & 3) ^ ((lane >> 3) & 3)) << 3;
  int q4s = (q4 ^ ((lh >> 1) & 3)) << 3;

#define STG64(BUF,K0)                                                          \
  {                                                                            \
    _Pragma("unroll") for (int i = 0; i < 2; ++i) {                            \
      int c = w * 2 + i;                                                       \
      cp16(A + (size_t)(tm + c * 16 + srow) * K + (K0) + scol,                 \
           lds + (BUF) * 6144 + c * 512);                                      \
    }                                                                          \
    cp16(B + (size_t)(tn + w * 16 + srow) * K + (K0) + scol,                   \
         lds + (BUF) * 6144 + 4096 + w * 512);                                 \
  }

  f32x4 acc[4][2] = {};
  const int nst = K >> 5;

  STG64(0, 0);

  for (int t = 0; t < nst; ++t) {
    const unsigned short* bse = lds + (t & 1) * 6144;
    __syncthreads();                 // vmcnt(0)+lgkmcnt(0)+s_barrier
    if (t + 1 < nst) STG64((t & 1) ^ 1, (t + 1) << 5);
    bf16x8 afr[4], bfr[2];
#pragma unroll
    for (int r = 0; r < 4; ++r)
      afr[r] = *(const bf16x8*)(bse + (wm + r * 16 + lh) * 32 + q4s);
#pragma unroll
    for (int c = 0; c < 2; ++c)
      bfr[c] = *(const bf16x8*)(bse + 4096 + (wn + c * 16 + lh) * 32 + q4s);
    __builtin_amdgcn_s_setprio(1);
#pragma unroll
    for (int r = 0; r < 4; ++r)
#pragma unroll
      for (int c = 0; c < 2; ++c)
        acc[r][c] = MFMA32(afr[r], bfr[c], acc[r][c]);
    __builtin_amdgcn_s_setprio(0);
  }
#undef STG64

#pragma unroll
  for (int r = 0; r < 4; ++r)
#pragma unroll
    for (int c = 0; c < 2; ++c)
#pragma unroll
      for (int e = 0; e < 4; ++e) {
        int row = tm + wm + r * 16 + q4 * 4 + e;
        int col = tn + wn + c * 16 + lh;
        if (Cb) Cb[(size_t)row * N + col] = f2bf(acc[r][c][e] * scale);
        else    Cf[(size_t)row * N + col] = acc[r][c][e] * scale;
      }
}

// ---------- attention v4 (round-5 proven): LDS-staged K/V, register P -------
__global__ __launch_bounds__(256) void attn_kernel(
    const unsigned short* __restrict__ Q, const unsigned short* __restrict__ Kp,
    const unsigned short* __restrict__ VT, const float* __restrict__ bz,
    float* __restrict__ po, float* __restrict__ lp)
{
  __shared__ __attribute__((aligned(16))) unsigned short Klds[4096]; // [64 tok][8 blk of 8]
  __shared__ __attribute__((aligned(16))) unsigned short Vlds[4096]; // [64 d][8 blk of 8]
  int w = threadIdx.x >> 6, lane = threadIdx.x & 63;
  int lh = lane & 15, q4 = lane >> 4;

  // XCD swizzle: same-bh blocks land on same XCD (bh & 7 == xcd)
  int id = blockIdx.x;
  int xcd = id & 7, j = id >> 3;
  int ql = j & 7;                   // 8 blocks per bh
  int half = ql & 1, qt = ql >> 1;  // token half, q-tile
  int bh = (j >> 3) * 8 + xcd;
  int b = bh >> 4, h = bh & 15;
  int q0 = qt * 128;
  int t00 = half * 2048;

  const unsigned short* Qb = Q + (size_t)(b * 512 + q0 + w * 32) * 1024 + h * 64;
  const unsigned short* Kb = Kp + (size_t)(b * 4096) * 1024 + h * 64;
  const unsigned short* Vb = VT + (size_t)(h * 64) * 16384 + b * 4096;
  const float* bzg = bz + (size_t)b * 4096;

  // Q B-operand fragments: 2 strips of 16 q-rows
  bf16x8 bq[2][2];
#pragma unroll
  for (int s = 0; s < 2; ++s)
#pragma unroll
    for (int th = 0; th < 2; ++th)
      bq[s][th] = *(const bf16x8*)(Qb + (size_t)(s * 16 + lh) * 1024 + th * 32 + q4 * 8);

  f32x4 oa[2][4] = {};              // O^T accumulators [strip][d-tile]
  float ls[2] = {0.f, 0.f};

  int rl = lane >> 3, blk = lane & 7;
  int sw = ((blk ^ rl) * 8);        // xor-swizzled 8-ushort block offset in source row

  for (int ti = 0; ti < 32; ++ti) {
    int t = t00 + ti * 64;
    // ---- stage K[64 tok][64 d] and V^T[64 d][64 tok], xor-swizzled blocks ----
#pragma unroll
    for (int r = 0; r < 2; ++r) {
      int seg = r * 4 + w;
      int row = seg * 8 + rl;
      cp16(Kb + (size_t)(t + row) * 1024 + sw, Klds + seg * 512);
      cp16(Vb + (size_t)row * 16384 + t + sw, Vlds + seg * 512);
    }
    __syncthreads();

    // bias (pre-transformed) for this tile's tokens
    float4 bz4[4];
#pragma unroll
    for (int c = 0; c < 4; ++c)
      bz4[c] = *(const float4*)(bzg + t + c * 16 + q4 * 4);

    // K fragments: A[m=tok][k=d], lane m=lh, k=th*32+q4*8..+8
    bf16x8 kf[4][2];
#pragma unroll
    for (int c = 0; c < 4; ++c)
#pragma unroll
      for (int th = 0; th < 2; ++th)
        kf[c][th] = *(const bf16x8*)(Klds + (c * 16 + lh) * 64 + (((th << 2) + q4) ^ (lh & 7)) * 8);
    // V fragments: A[m=d][k=tok], lane m=lh (+c2*16), k=c*16+q4*4..+4
    bf16x4 vf[4][4];
#pragma unroll
    for (int c = 0; c < 4; ++c)
#pragma unroll
      for (int c2 = 0; c2 < 4; ++c2)
        vf[c][c2] = *(const bf16x4*)(Vlds + (c2 * 16 + lh) * 64 +
                                     (((c << 1) + (q4 >> 1)) ^ (lh & 7)) * 8 + (q4 & 1) * 4);

#pragma unroll
    for (int s = 0; s < 2; ++s) {
#pragma unroll
      for (int c = 0; c < 4; ++c) {
        f32x4 z = {};
        z = MFMA32(kf[c][0], bq[s][0], z);
        z = MFMA32(kf[c][1], bq[s][1], z);
        float bzf[4] = {bz4[c].x, bz4[c].y, bz4[c].z, bz4[c].w};
        bf16x4 pb;
        float ps = 0.f;
#pragma unroll
        for (int e = 0; e < 4; ++e) {
          float p = __builtin_amdgcn_exp2f(z[e] + bzf[e]);
          ps += p;
          pb[e] = (short)f2bf(p);
        }
        ls[s] += ps;
#pragma unroll
        for (int c2 = 0; c2 < 4; ++c2)
          oa[s][c2] = MFMA16(vf[c][c2], pb, oa[s][c2]);
      }
    }
    __syncthreads();
  }

  // l: lane holds partial for q=lh; reduce across the 4 q4 groups
#pragma unroll
  for (int s = 0; s < 2; ++s) {
    ls[s] += __shfl_xor(ls[s], 16);
    ls[s] += __shfl_xor(ls[s], 32);
  }

  // partial stores: po[half*256 + bh*4+qt][d=64][q=128]
  int sl = bh * 4 + qt;
  float* pslice = po + (size_t)(half * 256 + sl) * 8192;
#pragma unroll
  for (int s = 0; s < 2; ++s) {
    if (q4 == 0) lp[half * 32768 + sl * 128 + w * 32 + s * 16 + lh] = ls[s];
#pragma unroll
    for (int c2 = 0; c2 < 4; ++c2)
#pragma unroll
      for (int e = 0; e < 4; ++e)
        pslice[(c2 * 16 + q4 * 4 + e) * 128 + w * 32 + s * 16 + lh] = oa[s][c2][e];
  }
}

// ---------- merge token-half partials, normalize, pack to bf16 ao ----------
__global__ void norm_kernel(const float* __restrict__ po, const float* __restrict__ lp,
                            unsigned short* __restrict__ ao) {
  int g = blockIdx.x * 256 + threadIdx.x;   // 262144 threads
  int d8 = (g & 7) * 8;
  int rowid = g >> 3;                        // 0..32767 = bh*512 + qt*128 + qcol
  int bh = rowid >> 9, rq = rowid & 511, qt = rq >> 7, qcol = rq & 127;
  int sl = bh * 4 + qt;
  const float* p0 = po + (size_t)sl * 8192;
  const float* p1 = po + (size_t)(256 + sl) * 8192;
  float l = lp[sl * 128 + qcol] + lp[32768 + sl * 128 + qcol];
  float inv = 1.f / l;
  unsigned short o8[8];
#pragma unroll
  for (int k = 0; k < 8; ++k)
    o8[k] = f2bf((p0[(d8 + k) * 128 + qcol] + p1[(d8 + k) * 128 + qcol]) * inv);
  int b = bh >> 4, h = bh & 15;
  unsigned short* dst = ao + (size_t)(b * 512 + qt * 128 + qcol) * 1024 + h * 64 + d8;
  *(ushort4*)dst = *(ushort4*)o8;
  *(ushort4*)(dst + 4) = *(ushort4*)(o8 + 4);
}

// ---------- launch ----------
extern "C" void kernel_launch(void* const* d_in, const int* in_sizes, int n_in,
                              void* d_out, int out_size, void* d_ws, size_t ws_size,
                              hipStream_t stream) {
  const float* query  = (const float*)d_in[0];
  const float* memory = (const float*)d_in[1];
  const float* bias   = (const float*)d_in[2];
  const float* Wq     = (const float*)d_in[3];
  const float* Wk     = (const float*)d_in[4];
  const float* Wv     = (const float*)d_in[5];
  const float* Wo     = (const float*)d_in[6];
  float* out = (float*)d_out;

  unsigned short* ws  = (unsigned short*)d_ws;
  unsigned short* qbf = ws;                       // 2048*1024
  unsigned short* mbf = qbf + 2097152;            // 16384*1024
  unsigned short* WqT = mbf + 16777216;           // 4 x 1024*1024 contiguous
  unsigned short* WkT = WqT + 1048576;
  unsigned short* WvT = WkT + 1048576;
  unsigned short* WoT = WvT + 1048576;
  unsigned short* qp  = WoT + 1048576;            // 2048*1024 (scaled q proj)
  unsigned short* kp  = qp + 2097152;             // 16384*1024
  unsigned short* vT  = kp + 16777216;            // 1024*16384
  unsigned short* ao  = vT + 16777216;            // 2048*1024
  float* bzw = (float*)(ao + 2097152);            // 16384 floats (bias*log2e-16)
  // po/lp alias qbf+mbf (dead after the projection GEMMs)
  float* po = (float*)ws;                         // 512 slices x 8192 floats = 16 MB
  float* lp = po + 4194304;                       // 65536 floats

  conv_both<<<18448, 256, 0, stream>>>(query, memory, bias, qbf, mbf, bzw);
  transpose4<<<dim3(32, 32, 4), dim3(32, 8), 0, stream>>>(Wq, Wk, Wv, Wo, WqT);

  // q = (query@Wq) * (1/8)*log2e   [2048 x 1024]
  gemm_bt64<<<dim3(16, 16), 256, 0, stream>>>(qbf, WqT, nullptr, qp, 2048, 1024, 1024, 0.125f * LOG2E);
  // fused: kp = memory@Wk, vT = (memory@Wv)^T  — single-sync dbuf, 512 thr
  gemm_kv<<<512, 512, 0, stream>>>(mbf, WkT, WvT, kp, vT);

  attn_kernel<<<512, 256, 0, stream>>>(qp, kp, vT, bzw, po, lp);
  norm_kernel<<<1024, 256, 0, stream>>>(po, lp, ao);

  // out = ao @ Wo (fp32 out)
  gemm_bt64<<<dim3(16, 16), 256, 0, stream>>>(ao, WoT, out, nullptr, 2048, 1024, 1024, 1.f);
}